// Round 1
// baseline (111.762 us; speedup 1.0000x reference)
//
#include <hip/hip_runtime.h>
#include <math.h>

#define EPSF    1e-8f
#define W_MINF  0.005f
#define BETAF   0.02f
#define LOG2E   1.4426950408889634f
#define KEXP    (LOG2E / BETAF)   /* 72.1347520444 */

__device__ __forceinline__ float fast_exp(float x) {   // e^x
    return __builtin_amdgcn_exp2f(x * LOG2E);
}
__device__ __forceinline__ float sigm(float x) {       // 1/(1+e^-x)
    return 1.0f / (1.0f + fast_exp(-x));
}

extern "C" __global__ __launch_bounds__(256)
void voronoi_kernel(const float* __restrict__ uv,
                    const float* __restrict__ seeds,
                    const float* __restrict__ w_raw,
                    const float* __restrict__ h_raw,
                    const float* __restrict__ theta,
                    const float* __restrict__ a_raw,
                    const float* __restrict__ gap_thr_raw,
                    const float* __restrict__ big_thr_raw,
                    const float* __restrict__ alpha_raw,
                    const float* __restrict__ eta_raw,
                    float* __restrict__ out,
                    int Q, int S)
{
    // Per-seed staged data: x, y, cos, sin, a^2, 1/a^2 (stride 8 for b128/b64 reads)
    __shared__ float sdat[512 * 8];
    const int tid = threadIdx.x;

    for (int j = tid; j < S; j += (int)blockDim.x) {
        float sx = seeds[2 * j + 0];
        float sy = seeds[2 * j + 1];
        float sn, cs;
        __sincosf(theta[j], &sn, &cs);
        float a  = 0.5f + 1.5f * sigm(a_raw[j]);
        float a2 = a * a;
        sdat[j * 8 + 0] = sx;
        sdat[j * 8 + 1] = sy;
        sdat[j * 8 + 2] = cs;
        sdat[j * 8 + 3] = sn;
        sdat[j * 8 + 4] = a2;
        sdat[j * 8 + 5] = 1.0f / a2;
        sdat[j * 8 + 6] = 0.0f;
        sdat[j * 8 + 7] = 0.0f;
    }
    __syncthreads();

    const int q = blockIdx.x * blockDim.x + tid;
    if (q >= Q) return;

    const float ux = uv[2 * q + 0];
    const float uy = uv[2 * q + 1];

    float d1 = 1e30f, d2 = 1e30f;
    int   i1 = 0,     i2 = 0;
    float s1 = 0.0f,  s2 = 0.0f;   // online softmax: sum e, sum e^2 (rel. to running min)

    #pragma unroll 4
    for (int j = 0; j < S; ++j) {
        const float4 p0 = *reinterpret_cast<const float4*>(&sdat[j * 8]);
        const float2 p1 = *reinterpret_cast<const float2*>(&sdat[j * 8 + 4]);
        float dx = ux - p0.x;
        float dy = uy - p0.y;
        float du = fmaf(p0.z, dx,  p0.w * dy);   //  c*dx + s*dy
        float dv = fmaf(p0.z, dy, -(p0.w * dx)); //  c*dy - s*dx
        float d  = __builtin_amdgcn_sqrtf(fmaf(du * du, p1.x,
                                          fmaf(dv * dv, p1.y, EPSF)));
        float d1o = d1;
        bool lt1 = d < d1;
        bool lt2 = d < d2;
        d2 = lt2 ? d   : d2;   i2 = lt2 ? j  : i2;
        d2 = lt1 ? d1o : d2;   i2 = lt1 ? i1 : i2;
        d1 = lt1 ? d   : d1;   i1 = lt1 ? j  : i1;
        // rescale factor f = exp((d1_new - d1_old)/beta)  (==1 when min unchanged)
        float f = __builtin_amdgcn_exp2f((d1 - d1o) * KEXP);
        float e = __builtin_amdgcn_exp2f((d1 - d)   * KEXP);
        s1 = fmaf(s1, f,     e);
        s2 = fmaf(s2, f * f, e * e);
    }

    float gap  = d2 - d1;
    float sp2  = s2 / (s1 * s1);           // sum p^2
    float keff = 1.0f / (sp2 + EPSF);
    float jfac = sigm((keff - 3.0f) * (1.0f / 0.35f));

    // w_pair = 0.5*(w_geo[i1,i2] + w_geo[i2,i1]), dist part is symmetric
    float ddx   = sdat[i1 * 8 + 0] - sdat[i2 * 8 + 0];
    float ddy   = sdat[i1 * 8 + 1] - sdat[i2 * 8 + 1];
    float pdist = __builtin_amdgcn_sqrtf(fmaf(ddx, ddx, fmaf(ddy, ddy, EPSF)));
    float wmax  = fmaxf(0.8f * pdist, W_MINF + EPSF);
    float sij   = sigm(w_raw[i1 * S + i2] * 0.2f);   // /RAW_TEMP(5)
    float sji   = sigm(w_raw[i2 * S + i1] * 0.2f);
    float wpair = W_MINF + (wmax - W_MINF) * 0.5f * (sij + sji);

    float weff     = wpair * fmaf(0.15f, jfac, 1.0f);
    float beta_eff = BETAF * fmaf(0.05f, jfac, 1.0f);
    float wall     = sigm((weff - gap) / beta_eff);

    float gap_thr = 0.5f  * sigm(gap_thr_raw[0]);          // [0, 0.5]
    float big_thr = 0.6f  * sigm(big_thr_raw[0]);          // [0, 0.6]
    float alpha_g = 0.01f + 0.19f * sigm(alpha_raw[0]);    // [0.01, 0.2]
    float eta_g   = 0.01f + 0.19f * sigm(eta_raw[0]);      // [0.01, 0.2]

    float gate = sigm((gap_thr - gap) / alpha_g) * sigm((big_thr - d1) / eta_g);

    float t      = fmaxf(keff - 3.0f, 0.0f);
    float triple = 0.15f * t * __builtin_amdgcn_sqrtf(t);  // t^1.5

    float h   = 0.5f + 1.5f * sigm(h_raw[0]);
    float occ = fminf(fmaxf(fmaf(wall, gate, triple), 0.0f), 1.0f);
    out[q] = occ * h;
}

extern "C" void kernel_launch(void* const* d_in, const int* in_sizes, int n_in,
                              void* d_out, int out_size, void* d_ws, size_t ws_size,
                              hipStream_t stream)
{
    const float* uv          = (const float*)d_in[0];
    const float* seeds_raw   = (const float*)d_in[1];
    const float* w_raw       = (const float*)d_in[2];
    const float* h_raw       = (const float*)d_in[3];
    const float* theta       = (const float*)d_in[4];
    const float* a_raw       = (const float*)d_in[5];
    const float* gap_thr_raw = (const float*)d_in[6];
    const float* big_thr_raw = (const float*)d_in[7];
    const float* alpha_raw   = (const float*)d_in[8];
    const float* eta_raw     = (const float*)d_in[9];
    float* out = (float*)d_out;

    const int Q = in_sizes[0] / 2;
    const int S = in_sizes[4];

    dim3 block(256);
    dim3 grid((Q + 255) / 256);
    voronoi_kernel<<<grid, block, 0, stream>>>(uv, seeds_raw, w_raw, h_raw, theta,
                                               a_raw, gap_thr_raw, big_thr_raw,
                                               alpha_raw, eta_raw, out, Q, S);
}

// Round 2
// 98.444 us; speedup vs baseline: 1.1353x; 1.1353x over previous
//
#include <hip/hip_runtime.h>
#include <math.h>

#define EPSF    1e-8f
#define W_MINF  0.005f
#define BETAF   0.02f
#define LOG2E   1.4426950408889634f
#define KEXP    (LOG2E / BETAF)   /* 72.1347520444 */

__device__ __forceinline__ float fast_exp(float x) {   // e^x
    return __builtin_amdgcn_exp2f(x * LOG2E);
}
__device__ __forceinline__ float sigm(float x) {       // 1/(1+e^-x)
    return 1.0f / (1.0f + fast_exp(-x));
}

// 4 threads per query; each handles 128 of 512 seeds (interleaved), then
// shfl-xor merge of top-2 + online-softmax state.
extern "C" __global__ __launch_bounds__(256)
void voronoi_kernel(const float* __restrict__ uv,
                    const float* __restrict__ seeds,
                    const float* __restrict__ w_raw,
                    const float* __restrict__ h_raw,
                    const float* __restrict__ theta,
                    const float* __restrict__ a_raw,
                    const float* __restrict__ gap_thr_raw,
                    const float* __restrict__ big_thr_raw,
                    const float* __restrict__ alpha_raw,
                    const float* __restrict__ eta_raw,
                    float* __restrict__ out,
                    int Q, int S)
{
    // Per-seed: x, y, c*a, s*a, c/a, s/a  (stride 8 floats for alignment)
    __shared__ float sdat[512 * 8];
    const int tid = threadIdx.x;

    for (int j = tid; j < S; j += (int)blockDim.x) {
        float sx = seeds[2 * j + 0];
        float sy = seeds[2 * j + 1];
        float sn, cs;
        __sincosf(theta[j], &sn, &cs);
        float a  = 0.5f + 1.5f * sigm(a_raw[j]);
        float ia = 1.0f / a;
        sdat[j * 8 + 0] = sx;
        sdat[j * 8 + 1] = sy;
        sdat[j * 8 + 2] = cs * a;
        sdat[j * 8 + 3] = sn * a;
        sdat[j * 8 + 4] = cs * ia;
        sdat[j * 8 + 5] = sn * ia;
        sdat[j * 8 + 6] = 0.0f;
        sdat[j * 8 + 7] = 0.0f;
    }
    __syncthreads();

    const int gid  = blockIdx.x * blockDim.x + tid;
    const int q    = gid >> 2;        // query index
    const int part = gid & 3;         // seed-partition within query
    if (q >= Q) return;

    const float ux = uv[2 * q + 0];
    const float uy = uv[2 * q + 1];

    float d1 = 1e30f, d2 = 1e30f;
    int   i1 = 0,     i2 = 0;
    float s1 = 0.0f,  s2 = 0.0f;   // sum e, sum e^2 relative to running local min

    #pragma unroll 4
    for (int jj = 0; jj < 128; ++jj) {
        const int j = 4 * jj + part;
        const float4 p0 = *reinterpret_cast<const float4*>(&sdat[j * 8]);
        const float2 p1 = *reinterpret_cast<const float2*>(&sdat[j * 8 + 4]);
        float dx = ux - p0.x;
        float dy = uy - p0.y;
        float du = fmaf(p0.z, dx,  p0.w * dy);    // (c*dx + s*dy)*a
        float dv = fmaf(p1.x, dy, -(p1.y * dx));  // (c*dy - s*dx)/a
        float d  = __builtin_amdgcn_sqrtf(fmaf(du, du, fmaf(dv, dv, EPSF)));

        float d1o = d1;
        bool lt1 = d < d1;
        bool lt2 = d < d2;
        d2 = lt2 ? d   : d2;   i2 = lt2 ? j  : i2;
        d2 = lt1 ? d1o : d2;   i2 = lt1 ? i1 : i2;
        d1 = lt1 ? d   : d1;   i1 = lt1 ? j  : i1;

        // one exp serves both roles: if min updated, g is the rescale factor
        // (new term is e^0=1); else g is the new term (rescale is 1).
        float g  = __builtin_amdgcn_exp2f(-fabsf(d - d1o) * KEXP);
        float g2 = g * g;
        float am  = lt1 ? g    : 1.0f;
        float bm  = lt1 ? 1.0f : g;
        float am2 = lt1 ? g2   : 1.0f;
        float bm2 = lt1 ? 1.0f : g2;
        s1 = fmaf(s1, am,  bm);
        s2 = fmaf(s2, am2, bm2);
    }

    // merge the 4 partitions (lanes part^1, then part^2)
    #pragma unroll
    for (int m = 1; m <= 2; m <<= 1) {
        float d1b = __shfl_xor(d1, m);
        float d2b = __shfl_xor(d2, m);
        int   i1b = __shfl_xor(i1, m);
        int   i2b = __shfl_xor(i2, m);
        float s1b = __shfl_xor(s1, m);
        float s2b = __shfl_xor(s2, m);

        bool aw = d1 <= d1b;                      // a-side wins the min
        float nd1 = aw ? d1 : d1b;
        int   ni1 = aw ? i1 : i1b;
        float c2a = aw ? d2  : d2b;               // winner's second
        int   c2ai= aw ? i2  : i2b;
        float c2b = aw ? d1b : d1;                // loser's first
        int   c2bi= aw ? i1b : i1;
        bool  sw  = c2a <= c2b;
        float nd2 = sw ? c2a  : c2b;
        int   ni2 = sw ? c2ai : c2bi;

        float fa = __builtin_amdgcn_exp2f((nd1 - d1)  * KEXP);  // <=1
        float fb = __builtin_amdgcn_exp2f((nd1 - d1b) * KEXP);
        s1 = fmaf(s1, fa, s1b * fb);
        s2 = fmaf(s2, fa * fa, s2b * (fb * fb));
        d1 = nd1; d2 = nd2; i1 = ni1; i2 = ni2;
    }

    float gap  = d2 - d1;
    float sp2  = s2 / (s1 * s1);           // sum p^2
    float keff = 1.0f / (sp2 + EPSF);
    float jfac = sigm((keff - 3.0f) * (1.0f / 0.35f));

    // w_pair = 0.5*(w_geo[i1,i2] + w_geo[i2,i1]); distance part symmetric
    float ddx   = sdat[i1 * 8 + 0] - sdat[i2 * 8 + 0];
    float ddy   = sdat[i1 * 8 + 1] - sdat[i2 * 8 + 1];
    float pdist = __builtin_amdgcn_sqrtf(fmaf(ddx, ddx, fmaf(ddy, ddy, EPSF)));
    float wmax  = fmaxf(0.8f * pdist, W_MINF + EPSF);
    float sij   = sigm(w_raw[i1 * S + i2] * 0.2f);   // /RAW_TEMP(5)
    float sji   = sigm(w_raw[i2 * S + i1] * 0.2f);
    float wpair = W_MINF + (wmax - W_MINF) * 0.5f * (sij + sji);

    float weff     = wpair * fmaf(0.15f, jfac, 1.0f);
    float beta_eff = BETAF * fmaf(0.05f, jfac, 1.0f);
    float wall     = sigm((weff - gap) / beta_eff);

    float gap_thr = 0.5f  * sigm(gap_thr_raw[0]);          // [0, 0.5]
    float big_thr = 0.6f  * sigm(big_thr_raw[0]);          // [0, 0.6]
    float alpha_g = 0.01f + 0.19f * sigm(alpha_raw[0]);    // [0.01, 0.2]
    float eta_g   = 0.01f + 0.19f * sigm(eta_raw[0]);      // [0.01, 0.2]

    float gate = sigm((gap_thr - gap) / alpha_g) * sigm((big_thr - d1) / eta_g);

    float t      = fmaxf(keff - 3.0f, 0.0f);
    float triple = 0.15f * t * __builtin_amdgcn_sqrtf(t);  // t^1.5

    float h   = 0.5f + 1.5f * sigm(h_raw[0]);
    float occ = fminf(fmaxf(fmaf(wall, gate, triple), 0.0f), 1.0f);
    if (part == 0) out[q] = occ * h;
}

extern "C" void kernel_launch(void* const* d_in, const int* in_sizes, int n_in,
                              void* d_out, int out_size, void* d_ws, size_t ws_size,
                              hipStream_t stream)
{
    const float* uv          = (const float*)d_in[0];
    const float* seeds_raw   = (const float*)d_in[1];
    const float* w_raw       = (const float*)d_in[2];
    const float* h_raw       = (const float*)d_in[3];
    const float* theta       = (const float*)d_in[4];
    const float* a_raw       = (const float*)d_in[5];
    const float* gap_thr_raw = (const float*)d_in[6];
    const float* big_thr_raw = (const float*)d_in[7];
    const float* alpha_raw   = (const float*)d_in[8];
    const float* eta_raw     = (const float*)d_in[9];
    float* out = (float*)d_out;

    const int Q = in_sizes[0] / 2;
    const int S = in_sizes[4];

    dim3 block(256);
    dim3 grid((Q * 4 + 255) / 256);   // 4 threads per query
    voronoi_kernel<<<grid, block, 0, stream>>>(uv, seeds_raw, w_raw, h_raw, theta,
                                               a_raw, gap_thr_raw, big_thr_raw,
                                               alpha_raw, eta_raw, out, Q, S);
}

// Round 3
// 93.541 us; speedup vs baseline: 1.1948x; 1.0524x over previous
//
#include <hip/hip_runtime.h>
#include <math.h>

#define EPSF    1e-8f
#define W_MINF  0.005f
#define BETAF   0.02f
#define LOG2E   1.4426950408889634f

constexpr double KD    = 1.4426950408889634 / 0.02;   // log2(e)/beta
constexpr float  K2F   = (float)(KD * KD);            // fold into A,B,C
constexpr float  K2EPS = (float)(KD * KD * 1e-8);     // scaled eps
constexpr float  INVK  = (float)(1.0 / KD);

__device__ __forceinline__ float fast_exp(float x) {   // e^x
    return __builtin_amdgcn_exp2f(x * LOG2E);
}
__device__ __forceinline__ float sigm(float x) {       // 1/(1+e^-x)
    return 1.0f / (1.0f + fast_exp(-x));
}
__device__ __forceinline__ float ex2(float x) { return __builtin_amdgcn_exp2f(x); }

// ---------------- kernel A: per-seed table (SoA: x,y,A,B,C) into d_ws ------
extern "C" __global__ __launch_bounds__(512)
void seed_prep(const float* __restrict__ seeds,
               const float* __restrict__ theta,
               const float* __restrict__ a_raw,
               float* __restrict__ ws, int S)
{
    int j = blockIdx.x * blockDim.x + threadIdx.x;
    if (j >= S) return;
    float sx = seeds[2 * j + 0];
    float sy = seeds[2 * j + 1];
    float sn, cs;
    __sincosf(theta[j], &sn, &cs);
    float a   = 0.5f + 1.5f * sigm(a_raw[j]);
    float a2  = a * a;
    float ia2 = 1.0f / a2;
    float c2 = cs * cs, s2 = sn * sn;
    ws[0 * 512 + j] = sx;
    ws[1 * 512 + j] = sy;
    ws[2 * 512 + j] = K2F * (c2 * a2 + s2 * ia2);          // A
    ws[3 * 512 + j] = K2F * (s2 * a2 + c2 * ia2);          // B
    ws[4 * 512 + j] = K2F * (cs * sn * (a2 - ia2));        // C
}

// ---------------- kernel B: 8 waves per 64-query set, SGPR seed broadcast --
extern "C" __global__ __launch_bounds__(512)
void voronoi_kernel(const float* __restrict__ uv,
                    const float* __restrict__ w_raw,
                    const float* __restrict__ h_raw,
                    const float* __restrict__ gap_thr_raw,
                    const float* __restrict__ big_thr_raw,
                    const float* __restrict__ alpha_raw,
                    const float* __restrict__ eta_raw,
                    const float* __restrict__ ws,
                    float* __restrict__ out,
                    int Q, int S)
{
    // seed table (SoA, wave-uniform accesses -> s_load)
    const float* __restrict__ tx = ws + 0 * 512;
    const float* __restrict__ ty = ws + 1 * 512;
    const float* __restrict__ tA = ws + 2 * 512;
    const float* __restrict__ tB = ws + 3 * 512;
    const float* __restrict__ tC = ws + 4 * 512;

    const int part = __builtin_amdgcn_readfirstlane((int)(threadIdx.x >> 6));
    const int lane = threadIdx.x & 63;
    const int q    = blockIdx.x * 64 + lane;
    const int qc   = q < Q ? q : (Q - 1);

    const float ux = uv[2 * qc + 0];
    const float uy = uv[2 * qc + 1];

    unsigned v1 = 0x7F7FFFFFu, v2 = 0x7F7FFFFFu;  // packed (d-bits|index)
    float s1 = 0.0f, s2 = 0.0f;                   // online softmax sums

    const int base = part * 64;
    #pragma unroll 8
    for (int t = 0; t < 64; ++t) {
        const int j = base + t;                   // uniform -> scalar loads
        const float sx = tx[j], sy = ty[j];
        const float A = tA[j], B = tB[j], C = tC[j];
        float dx = ux - sx;
        float dy = uy - sy;
        float p  = fmaf(A, dx, C * dy);
        float qq = fmaf(C, dx, B * dy);
        float r  = fmaf(dx, p, fmaf(dy, qq, K2EPS));
        float d  = __builtin_amdgcn_sqrtf(r);     // K-scaled distance

        unsigned pv  = (__float_as_uint(d) & 0xFFFFFE00u) | (unsigned)j;
        unsigned v1o = v1;
        v1 = v1 < pv ? v1 : pv;
        unsigned mx = v1o > pv ? v1o : pv;
        v2 = mx < v2 ? mx : v2;

        float mo = __uint_as_float(v1o);
        float mn = __uint_as_float(v1);
        float am = ex2(mn - mo);                  // rescale (1 if min kept)
        float bm = ex2(mn - d);                   // new term
        s1 = fmaf(s1, am, bm);
        s2 = fmaf(s2, am * am, bm * bm);
    }

    // ---- merge the 8 per-wave partials through LDS ----
    __shared__ unsigned mv1[8][64], mv2[8][64];
    __shared__ float    ms1[8][64], ms2[8][64];
    mv1[part][lane] = v1;  mv2[part][lane] = v2;
    ms1[part][lane] = s1;  ms2[part][lane] = s2;
    __syncthreads();
    if (part != 0) return;

    unsigned V1 = mv1[0][lane], V2 = mv2[0][lane];
    float    S1 = ms1[0][lane], S2 = ms2[0][lane];
    #pragma unroll
    for (int p2 = 1; p2 < 8; ++p2) {
        unsigned w1 = mv1[p2][lane], w2 = mv2[p2][lane];
        float    t1 = ms1[p2][lane], t2 = ms2[p2][lane];
        unsigned n1 = V1 < w1 ? V1 : w1;
        unsigned hi = V1 > w1 ? V1 : w1;
        unsigned lo2 = V2 < w2 ? V2 : w2;
        unsigned n2 = hi < lo2 ? hi : lo2;
        float fa = ex2(__uint_as_float(n1) - __uint_as_float(V1));
        float fb = ex2(__uint_as_float(n1) - __uint_as_float(w1));
        S1 = fmaf(S1, fa, t1 * fb);
        S2 = fmaf(S2, fa * fa, t2 * (fb * fb));
        V1 = n1; V2 = n2;
    }

    const int i1 = (int)(V1 & 511u);
    const int i2 = (int)(V2 & 511u);
    float d1  = __uint_as_float(V1) * INVK;       // back to true units
    float gap = (__uint_as_float(V2) - __uint_as_float(V1)) * INVK;

    float sp2  = S2 / (S1 * S1);                  // sum p^2
    float keff = 1.0f / (sp2 + EPSF);
    float jfac = sigm((keff - 3.0f) * (1.0f / 0.35f));

    float ddx   = tx[i1] - tx[i2];
    float ddy   = ty[i1] - ty[i2];
    float pdist = __builtin_amdgcn_sqrtf(fmaf(ddx, ddx, fmaf(ddy, ddy, EPSF)));
    float wmax  = fmaxf(0.8f * pdist, W_MINF + EPSF);
    float sij   = sigm(w_raw[i1 * S + i2] * 0.2f);   // /RAW_TEMP(5)
    float sji   = sigm(w_raw[i2 * S + i1] * 0.2f);
    float wpair = W_MINF + (wmax - W_MINF) * 0.5f * (sij + sji);

    float weff     = wpair * fmaf(0.15f, jfac, 1.0f);
    float beta_eff = BETAF * fmaf(0.05f, jfac, 1.0f);
    float wall     = sigm((weff - gap) / beta_eff);

    float gap_thr = 0.5f  * sigm(gap_thr_raw[0]);
    float big_thr = 0.6f  * sigm(big_thr_raw[0]);
    float alpha_g = 0.01f + 0.19f * sigm(alpha_raw[0]);
    float eta_g   = 0.01f + 0.19f * sigm(eta_raw[0]);

    float gate = sigm((gap_thr - gap) / alpha_g) * sigm((big_thr - d1) / eta_g);

    float t      = fmaxf(keff - 3.0f, 0.0f);
    float triple = 0.15f * t * __builtin_amdgcn_sqrtf(t);

    float h   = 0.5f + 1.5f * sigm(h_raw[0]);
    float occ = fminf(fmaxf(fmaf(wall, gate, triple), 0.0f), 1.0f);
    if (q < Q) out[q] = occ * h;
}

extern "C" void kernel_launch(void* const* d_in, const int* in_sizes, int n_in,
                              void* d_out, int out_size, void* d_ws, size_t ws_size,
                              hipStream_t stream)
{
    const float* uv          = (const float*)d_in[0];
    const float* seeds_raw   = (const float*)d_in[1];
    const float* w_raw       = (const float*)d_in[2];
    const float* h_raw       = (const float*)d_in[3];
    const float* theta       = (const float*)d_in[4];
    const float* a_raw       = (const float*)d_in[5];
    const float* gap_thr_raw = (const float*)d_in[6];
    const float* big_thr_raw = (const float*)d_in[7];
    const float* alpha_raw   = (const float*)d_in[8];
    const float* eta_raw     = (const float*)d_in[9];
    float* out = (float*)d_out;
    float* ws  = (float*)d_ws;

    const int Q = in_sizes[0] / 2;
    const int S = in_sizes[4];

    seed_prep<<<dim3((S + 511) / 512), dim3(512), 0, stream>>>(seeds_raw, theta,
                                                               a_raw, ws, S);

    dim3 block(512);                      // 8 waves: 8 seed-partitions
    dim3 grid((Q + 63) / 64);             // 64 queries per block
    voronoi_kernel<<<grid, block, 0, stream>>>(uv, w_raw, h_raw,
                                               gap_thr_raw, big_thr_raw,
                                               alpha_raw, eta_raw,
                                               ws, out, Q, S);
}

// Round 4
// 87.206 us; speedup vs baseline: 1.2816x; 1.0727x over previous
//
#include <hip/hip_runtime.h>
#include <math.h>

#define EPSF    1e-8f
#define W_MINF  0.005f
#define BETAF   0.02f
#define LOG2E   1.4426950408889634f

constexpr double KD    = 1.4426950408889634 / 0.02;   // log2(e)/beta
constexpr float  K2F   = (float)(KD * KD);            // folded into A,B,C
constexpr float  K2EPS = (float)(KD * KD * 1e-8);     // scaled eps
constexpr float  INVK  = (float)(1.0 / KD);

typedef float v2f __attribute__((ext_vector_type(2)));

__device__ __forceinline__ float fast_exp(float x) {   // e^x
    return __builtin_amdgcn_exp2f(x * LOG2E);
}
__device__ __forceinline__ float sigm(float x) {       // 1/(1+e^-x)
    return 1.0f / (1.0f + fast_exp(-x));
}
__device__ __forceinline__ float ex2(float x) { return __builtin_amdgcn_exp2f(x); }

// ---------------- kernel A: per-seed table (SoA: x,y,A,B,C) into d_ws ------
extern "C" __global__ __launch_bounds__(512)
void seed_prep(const float* __restrict__ seeds,
               const float* __restrict__ theta,
               const float* __restrict__ a_raw,
               float* __restrict__ ws, int S)
{
    int j = blockIdx.x * blockDim.x + threadIdx.x;
    if (j >= S) return;
    float sx = seeds[2 * j + 0];
    float sy = seeds[2 * j + 1];
    float sn, cs;
    __sincosf(theta[j], &sn, &cs);
    float a   = 0.5f + 1.5f * sigm(a_raw[j]);
    float a2  = a * a;
    float ia2 = 1.0f / a2;
    float c2 = cs * cs, s2 = sn * sn;
    ws[0 * 512 + j] = sx;
    ws[1 * 512 + j] = sy;
    ws[2 * 512 + j] = K2F * (c2 * a2 + s2 * ia2);          // A
    ws[3 * 512 + j] = K2F * (s2 * a2 + c2 * ia2);          // B
    ws[4 * 512 + j] = K2F * (cs * sn * (a2 - ia2));        // C
}

// ---------------- kernel B ------------------------------------------------
// 64 queries per block, 8 waves = 8 seed-partitions of 64 seeds each.
// Absolute-reference softmax (no online rescale): e = exp2(-K*d), terms for
// far seeds underflow to 0 exactly as they vanish in the reference softmax.
extern "C" __global__ __launch_bounds__(512)
void voronoi_kernel(const float* __restrict__ uv,
                    const float* __restrict__ w_raw,
                    const float* __restrict__ h_raw,
                    const float* __restrict__ gap_thr_raw,
                    const float* __restrict__ big_thr_raw,
                    const float* __restrict__ alpha_raw,
                    const float* __restrict__ eta_raw,
                    const float* __restrict__ ws,
                    float* __restrict__ out,
                    int Q, int S)
{
    const float* __restrict__ tx = ws + 0 * 512;
    const float* __restrict__ ty = ws + 1 * 512;
    const float* __restrict__ tA = ws + 2 * 512;
    const float* __restrict__ tB = ws + 3 * 512;
    const float* __restrict__ tC = ws + 4 * 512;

    const int part = __builtin_amdgcn_readfirstlane((int)(threadIdx.x >> 6));
    const int lane = threadIdx.x & 63;
    const int q    = blockIdx.x * 64 + lane;
    const int qc   = q < Q ? q : (Q - 1);

    const float2 u = *reinterpret_cast<const float2*>(&uv[2 * qc]);
    const v2f uxv = { u.x, u.x };
    const v2f uyv = { u.y, u.y };
    const v2f epsv = { K2EPS, K2EPS };

    unsigned v1u = 0x7F7FFFFFu, v2u = 0x7F7FFFFFu;  // packed (r-bits|index)
    v2f s1v = { 0.0f, 0.0f };
    v2f s2v = { 0.0f, 0.0f };

    const int base = part * 64;
    #pragma unroll 4
    for (int t = 0; t < 64; t += 2) {
        const int j = base + t;                   // wave-uniform
        const v2f sx = *reinterpret_cast<const v2f*>(&tx[j]);
        const v2f sy = *reinterpret_cast<const v2f*>(&ty[j]);
        const v2f A  = *reinterpret_cast<const v2f*>(&tA[j]);
        const v2f B  = *reinterpret_cast<const v2f*>(&tB[j]);
        const v2f C  = *reinterpret_cast<const v2f*>(&tC[j]);

        v2f dx = uxv - sx;
        v2f dy = uyv - sy;
        v2f p  = A * dx + C * dy;                 // pk_mul + pk_fma
        v2f qq = C * dx + B * dy;
        v2f r  = dx * p + (dy * qq + epsv);       // 2x pk_fma; r = (K*d)^2

        float nd0 = -__builtin_amdgcn_sqrtf(r.x); // -(K*d)
        float nd1 = -__builtin_amdgcn_sqrtf(r.y);
        v2f e = { ex2(nd0), ex2(nd1) };           // exp(-d/beta)
        s1v = s1v + e;                            // pk_add
        s2v = e * e + s2v;                        // pk_fma

        // top-2 on packed r (monotone with d); low 9 bits carry the index
        unsigned pv0 = (__float_as_uint(r.x) & 0xFFFFFE00u) | (unsigned)j;
        unsigned o0  = v1u;
        v1u = v1u < pv0 ? v1u : pv0;
        unsigned m0 = o0 > pv0 ? o0 : pv0;
        v2u = m0 < v2u ? m0 : v2u;

        unsigned pv1 = (__float_as_uint(r.y) & 0xFFFFFE00u) | (unsigned)(j + 1);
        unsigned o1  = v1u;
        v1u = v1u < pv1 ? v1u : pv1;
        unsigned m1 = o1 > pv1 ? o1 : pv1;
        v2u = m1 < v2u ? m1 : v2u;
    }

    float s1 = s1v.x + s1v.y;
    float s2 = s2v.x + s2v.y;

    // ---- merge 8 per-wave partials through LDS (plain sums + uint top-2) --
    __shared__ unsigned mv1[8][64], mv2[8][64];
    __shared__ float    ms1[8][64], ms2[8][64];
    mv1[part][lane] = v1u;  mv2[part][lane] = v2u;
    ms1[part][lane] = s1;   ms2[part][lane] = s2;
    __syncthreads();
    if (part != 0) return;

    unsigned V1 = mv1[0][lane], V2 = mv2[0][lane];
    float    S1 = ms1[0][lane], S2 = ms2[0][lane];
    #pragma unroll
    for (int p2 = 1; p2 < 8; ++p2) {
        unsigned w1 = mv1[p2][lane], w2 = mv2[p2][lane];
        S1 += ms1[p2][lane];
        S2 += ms2[p2][lane];
        unsigned n1 = V1 < w1 ? V1 : w1;
        unsigned hi = V1 > w1 ? V1 : w1;
        unsigned l2 = V2 < w2 ? V2 : w2;
        V2 = hi < l2 ? hi : l2;
        V1 = n1;
    }

    const int i1 = (int)(V1 & 511u);
    const int i2 = (int)(V2 & 511u);
    float d1K = __builtin_amdgcn_sqrtf(__uint_as_float(V1));   // K*d1
    float d2K = __builtin_amdgcn_sqrtf(__uint_as_float(V2));
    float d1  = d1K * INVK;
    float gap = (d2K - d1K) * INVK;

    float sp2  = (S2 / S1) / S1;                 // sum p^2 (underflow-safe)
    float keff = 1.0f / (sp2 + EPSF);
    float jfac = sigm((keff - 3.0f) * (1.0f / 0.35f));

    float ddx   = tx[i1] - tx[i2];
    float ddy   = ty[i1] - ty[i2];
    float pdist = __builtin_amdgcn_sqrtf(fmaf(ddx, ddx, fmaf(ddy, ddy, EPSF)));
    float wmax  = fmaxf(0.8f * pdist, W_MINF + EPSF);
    float sij   = sigm(w_raw[i1 * S + i2] * 0.2f);   // /RAW_TEMP(5)
    float sji   = sigm(w_raw[i2 * S + i1] * 0.2f);
    float wpair = W_MINF + (wmax - W_MINF) * 0.5f * (sij + sji);

    float weff     = wpair * fmaf(0.15f, jfac, 1.0f);
    float beta_eff = BETAF * fmaf(0.05f, jfac, 1.0f);
    float wall     = sigm((weff - gap) / beta_eff);

    float gap_thr = 0.5f  * sigm(gap_thr_raw[0]);
    float big_thr = 0.6f  * sigm(big_thr_raw[0]);
    float alpha_g = 0.01f + 0.19f * sigm(alpha_raw[0]);
    float eta_g   = 0.01f + 0.19f * sigm(eta_raw[0]);

    float gate = sigm((gap_thr - gap) / alpha_g) * sigm((big_thr - d1) / eta_g);

    float t      = fmaxf(keff - 3.0f, 0.0f);
    float triple = 0.15f * t * __builtin_amdgcn_sqrtf(t);

    float h   = 0.5f + 1.5f * sigm(h_raw[0]);
    float occ = fminf(fmaxf(fmaf(wall, gate, triple), 0.0f), 1.0f);
    if (q < Q) out[q] = occ * h;
}

extern "C" void kernel_launch(void* const* d_in, const int* in_sizes, int n_in,
                              void* d_out, int out_size, void* d_ws, size_t ws_size,
                              hipStream_t stream)
{
    const float* uv          = (const float*)d_in[0];
    const float* seeds_raw   = (const float*)d_in[1];
    const float* w_raw       = (const float*)d_in[2];
    const float* h_raw       = (const float*)d_in[3];
    const float* theta       = (const float*)d_in[4];
    const float* a_raw       = (const float*)d_in[5];
    const float* gap_thr_raw = (const float*)d_in[6];
    const float* big_thr_raw = (const float*)d_in[7];
    const float* alpha_raw   = (const float*)d_in[8];
    const float* eta_raw     = (const float*)d_in[9];
    float* out = (float*)d_out;
    float* ws  = (float*)d_ws;

    const int Q = in_sizes[0] / 2;
    const int S = in_sizes[4];

    seed_prep<<<dim3((S + 511) / 512), dim3(512), 0, stream>>>(seeds_raw, theta,
                                                               a_raw, ws, S);

    dim3 block(512);                      // 8 waves: 8 seed-partitions
    dim3 grid((Q + 63) / 64);             // 64 queries per block
    voronoi_kernel<<<grid, block, 0, stream>>>(uv, w_raw, h_raw,
                                               gap_thr_raw, big_thr_raw,
                                               alpha_raw, eta_raw,
                                               ws, out, Q, S);
}